// Round 3
// baseline (199.077 us; speedup 1.0000x reference)
//
#include <hip/hip_runtime.h>

constexpr int N_NODES = 10000;
constexpr int N_EDGES = 320000;
constexpr int IN_CH   = 128;
constexpr int HID     = 64;
constexpr int HEADS   = 4;
constexpr int OUT_CH  = 64;
constexpr int F1      = HEADS * HID;   // 256
constexpr float NEG_SLOPE = 0.2f;

// ---------------- CSR build ----------------

__global__ void k_zero2(int* __restrict__ counts, int* __restrict__ cursor) {
    int i = blockIdx.x * 256 + threadIdx.x;
    if (i < N_NODES) { counts[i] = 0; cursor[i] = 0; }
}

__global__ void k_count(const int* __restrict__ dst, int* __restrict__ counts) {
    int e = blockIdx.x * 256 + threadIdx.x;
    if (e < N_EDGES) atomicAdd(&counts[dst[e]], 1);
}

__global__ __launch_bounds__(1024) void k_scan(const int* __restrict__ counts,
                                               int* __restrict__ row_ptr) {
    __shared__ int wsum[16];
    __shared__ int s_carry;
    int tid = threadIdx.x, lane = tid & 63, w = tid >> 6;
    if (tid == 0) s_carry = 0;
    __syncthreads();
    for (int base = 0; base < N_NODES; base += 1024) {
        int i = base + tid;
        int v = (i < N_NODES) ? counts[i] : 0;
        int x = v;
        #pragma unroll
        for (int off = 1; off < 64; off <<= 1) {
            int t = __shfl_up(x, off, 64);
            if (lane >= off) x += t;
        }
        if (lane == 63) wsum[w] = x;
        __syncthreads();
        if (w == 0 && lane < 16) {
            int y = wsum[lane];
            #pragma unroll
            for (int off = 1; off < 16; off <<= 1) {
                int u = __shfl_up(y, off, 64);
                if (lane >= off) y += u;
            }
            wsum[lane] = y;
        }
        __syncthreads();
        int carry = s_carry;
        int woff = w ? wsum[w - 1] : 0;
        if (i < N_NODES) row_ptr[i] = carry + woff + x - v;
        int total = wsum[15];
        __syncthreads();
        if (tid == 0) s_carry = carry + total;
    }
    if (tid == 0) row_ptr[N_NODES] = s_carry;
}

__global__ void k_fill(const int* __restrict__ dst, const int* __restrict__ row_ptr,
                       int* __restrict__ cursor, int* __restrict__ edge_ids) {
    int e = blockIdx.x * 256 + threadIdx.x;
    if (e >= N_EDGES) return;
    int d = dst[e];
    int pos = row_ptr[d] + atomicAdd(&cursor[d], 1);
    edge_ids[pos] = e;
}

// ---------------- prep: WA[c][q] = sum_j W1[c, h*64+j]*a_{src|dst}[h,j]; de[0..4] ----

__global__ __launch_bounds__(1024) void k_prep(
        const float* __restrict__ W1, const float* __restrict__ as1,
        const float* __restrict__ ad1,
        const float* __restrict__ We1, const float* __restrict__ ae1,
        const float* __restrict__ We2, const float* __restrict__ ae2,
        float* __restrict__ WA, float* __restrict__ de) {
    int t = threadIdx.x;
    int c = t >> 3;         // 0..127
    int q = t & 7;          // 0..3 src heads, 4..7 dst heads
    int h = q & 3;
    const float* a = (q < 4) ? as1 : ad1;
    float s = 0.f;
    for (int j = 0; j < HID; ++j)
        s = fmaf(W1[(size_t)c * F1 + h * HID + j], a[h * HID + j], s);
    WA[c * 8 + q] = s;
    if (t < HEADS) {
        float v = 0.f;
        for (int j = 0; j < HID; ++j) v = fmaf(We1[t * HID + j], ae1[t * HID + j], v);
        de[t] = v;
    } else if (t == HEADS) {
        float v = 0.f;
        for (int j = 0; j < OUT_CH; ++j) v = fmaf(We2[j], ae2[j], v);
        de[HEADS] = v;
    }
}

// ---------------- dots1: [als|ald](n,h) = x @ WA ----------------

__global__ __launch_bounds__(256) void k_dots1(const float* __restrict__ x,
                                               const float* __restrict__ WA,
                                               float* __restrict__ als,
                                               float* __restrict__ ald) {
    __shared__ float xs[32][132];   // +4 pad: 16B-aligned rows, 4-way max conflict
    __shared__ float wa[IN_CH * 8];
    int tid = threadIdx.x;
    int row0 = blockIdx.x * 32;
    int nrows = N_NODES - row0; if (nrows > 32) nrows = 32;
    #pragma unroll
    for (int j = 0; j < 4; ++j) wa[tid + j * 256] = WA[tid + j * 256];
    const float4* xg = (const float4*)(x + (size_t)row0 * IN_CH);
    #pragma unroll
    for (int j = 0; j < 4; ++j) {
        int idx = tid + j * 256;      // f4 idx: row = idx>>5, c = (idx&31)*4
        int r = idx >> 5;
        if (r < nrows) {
            float4 v = xg[idx];
            *(float4*)&xs[r][(idx & 31) * 4] = v;
        }
    }
    __syncthreads();
    int r = tid >> 3, q = tid & 7;
    float s = 0.f;
    for (int c = 0; c < IN_CH; c += 4) {
        float4 xv = *(const float4*)&xs[r][c];
        s = fmaf(xv.x, wa[(c + 0) * 8 + q], s);
        s = fmaf(xv.y, wa[(c + 1) * 8 + q], s);
        s = fmaf(xv.z, wa[(c + 2) * 8 + q], s);
        s = fmaf(xv.w, wa[(c + 3) * 8 + q], s);
    }
    int n = row0 + r;
    if (r < nrows) {
        if (q < 4) als[n * 4 + q] = s;
        else       ald[n * 4 + (q - 4)] = s;
    }
}

// ---------------- per-edge alpha, layer 1 (CSR order) ----------------

__global__ void k_alpha1(const int* __restrict__ edge_ids, const int* __restrict__ src,
                         const int* __restrict__ dst, const float* __restrict__ ew,
                         const float* __restrict__ als, const float* __restrict__ ald,
                         const float* __restrict__ de,
                         float* __restrict__ exs, int* __restrict__ srcs) {
    int i = blockIdx.x * 256 + threadIdx.x;
    if (i >= N_EDGES) return;
    int e = edge_ids[i];
    int s = src[e], d = dst[e];
    float w = ew[e];
    float4 as = *(const float4*)(als + (size_t)s * HEADS);
    float4 ad = *(const float4*)(ald + (size_t)d * HEADS);
    float4 dev = *(const float4*)de;
    float4 a;
    a.x = as.x + ad.x + w * dev.x;
    a.y = as.y + ad.y + w * dev.y;
    a.z = as.z + ad.z + w * dev.z;
    a.w = as.w + ad.w + w * dev.w;
    a.x = a.x > 0.f ? a.x : NEG_SLOPE * a.x;
    a.y = a.y > 0.f ? a.y : NEG_SLOPE * a.y;
    a.z = a.z > 0.f ? a.z : NEG_SLOPE * a.z;
    a.w = a.w > 0.f ? a.w : NEG_SLOPE * a.w;
    a.x = __expf(a.x); a.y = __expf(a.y); a.z = __expf(a.z); a.w = __expf(a.w);
    *(float4*)(exs + (size_t)i * 4) = a;
    srcs[i] = s;
}

// ---------------- layer-1 aggregation in INPUT space ----------------
// wave per node; lane owns channels {2*lane, 2*lane+1} for all 4 heads.
// accbuf layout: [node][head][128]  (node*512 + h*128 + c)

__global__ __launch_bounds__(256) void k_aggx1(
        const float* __restrict__ x, const float* __restrict__ exs,
        const int* __restrict__ srcs, const int* __restrict__ row_ptr,
        float* __restrict__ accbuf) {
    int node = blockIdx.x * 4 + (threadIdx.x >> 6);
    int lane = threadIdx.x & 63;
    int c2 = lane * 2;
    float accx[4] = {0.f, 0.f, 0.f, 0.f};
    float accy[4] = {0.f, 0.f, 0.f, 0.f};
    float den[4]  = {0.f, 0.f, 0.f, 0.f};
    int beg = row_ptr[node], end = row_ptr[node + 1];
    int i = beg;
    for (; i + 8 <= end; i += 8) {
        int s[8];
        #pragma unroll
        for (int j = 0; j < 8; ++j) s[j] = srcs[i + j];
        float4 e[8];
        #pragma unroll
        for (int j = 0; j < 8; ++j) e[j] = *(const float4*)(exs + (size_t)(i + j) * 4);
        float2 xv[8];
        #pragma unroll
        for (int j = 0; j < 8; ++j)
            xv[j] = *(const float2*)(x + (size_t)s[j] * IN_CH + c2);
        #pragma unroll
        for (int j = 0; j < 8; ++j) {
            den[0] += e[j].x; den[1] += e[j].y; den[2] += e[j].z; den[3] += e[j].w;
            accx[0] = fmaf(e[j].x, xv[j].x, accx[0]);
            accy[0] = fmaf(e[j].x, xv[j].y, accy[0]);
            accx[1] = fmaf(e[j].y, xv[j].x, accx[1]);
            accy[1] = fmaf(e[j].y, xv[j].y, accy[1]);
            accx[2] = fmaf(e[j].z, xv[j].x, accx[2]);
            accy[2] = fmaf(e[j].z, xv[j].y, accy[2]);
            accx[3] = fmaf(e[j].w, xv[j].x, accx[3]);
            accy[3] = fmaf(e[j].w, xv[j].y, accy[3]);
        }
    }
    for (; i < end; ++i) {
        int s0 = srcs[i];
        float4 e0 = *(const float4*)(exs + (size_t)i * 4);
        float2 x0 = *(const float2*)(x + (size_t)s0 * IN_CH + c2);
        den[0] += e0.x; den[1] += e0.y; den[2] += e0.z; den[3] += e0.w;
        accx[0] = fmaf(e0.x, x0.x, accx[0]);
        accy[0] = fmaf(e0.x, x0.y, accy[0]);
        accx[1] = fmaf(e0.y, x0.x, accx[1]);
        accy[1] = fmaf(e0.y, x0.y, accy[1]);
        accx[2] = fmaf(e0.z, x0.x, accx[2]);
        accy[2] = fmaf(e0.z, x0.y, accy[2]);
        accx[3] = fmaf(e0.w, x0.x, accx[3]);
        accy[3] = fmaf(e0.w, x0.y, accy[3]);
    }
    #pragma unroll
    for (int h = 0; h < 4; ++h) {
        float inv = 1.f / (den[h] + 1e-16f);
        float2 o = make_float2(accx[h] * inv, accy[h] * inv);
        *(float2*)(accbuf + ((size_t)node * 4 + h) * IN_CH + c2) = o;
    }
}

// ---------------- h1 = blockdiag(accbuf @ W1_h) + b1, ELU ----------------
// 32 rows/block; wave -> 8 rows; lane: head = lane>>4, 4 cols.

__global__ __launch_bounds__(256) void k_hgemm1(
        const float* __restrict__ A, const float* __restrict__ W,
        const float* __restrict__ bias, float* __restrict__ h1) {
    int row0 = blockIdx.x * 32;
    int wv = threadIdx.x >> 6, lane = threadIdx.x & 63;
    int h = lane >> 4;
    int col = h * HID + (lane & 15) * 4;
    const float* Ap = A + ((size_t)(row0 + wv * 8) * 4 + h) * IN_CH;
    float acc[8][4];
    #pragma unroll
    for (int m = 0; m < 8; ++m)
        #pragma unroll
        for (int j = 0; j < 4; ++j) acc[m][j] = 0.f;
    for (int k = 0; k < IN_CH; k += 4) {
        float4 w0 = *(const float4*)(W + (size_t)(k + 0) * F1 + col);
        float4 w1 = *(const float4*)(W + (size_t)(k + 1) * F1 + col);
        float4 w2 = *(const float4*)(W + (size_t)(k + 2) * F1 + col);
        float4 w3 = *(const float4*)(W + (size_t)(k + 3) * F1 + col);
        #pragma unroll
        for (int m = 0; m < 8; ++m) {
            float4 av = *(const float4*)(Ap + (size_t)m * 512 + k);
            acc[m][0] = fmaf(av.x, w0.x, fmaf(av.y, w1.x, fmaf(av.z, w2.x, fmaf(av.w, w3.x, acc[m][0]))));
            acc[m][1] = fmaf(av.x, w0.y, fmaf(av.y, w1.y, fmaf(av.z, w2.y, fmaf(av.w, w3.y, acc[m][1]))));
            acc[m][2] = fmaf(av.x, w0.z, fmaf(av.y, w1.z, fmaf(av.z, w2.z, fmaf(av.w, w3.z, acc[m][2]))));
            acc[m][3] = fmaf(av.x, w0.w, fmaf(av.y, w1.w, fmaf(av.z, w2.w, fmaf(av.w, w3.w, acc[m][3]))));
        }
    }
    #pragma unroll
    for (int m = 0; m < 8; ++m) {
        int n = row0 + wv * 8 + m;
        if (n < N_NODES) {
            float4 o;
            o.x = acc[m][0] + bias[col + 0];
            o.y = acc[m][1] + bias[col + 1];
            o.z = acc[m][2] + bias[col + 2];
            o.w = acc[m][3] + bias[col + 3];
            o.x = o.x > 0.f ? o.x : expm1f(o.x);
            o.y = o.y > 0.f ? o.y : expm1f(o.y);
            o.z = o.z > 0.f ? o.z : expm1f(o.z);
            o.w = o.w > 0.f ? o.w : expm1f(o.w);
            *(float4*)(h1 + (size_t)n * F1 + col) = o;
        }
    }
}

// ---------------- GEMM2 + fused dots2 ----------------

__global__ __launch_bounds__(256) void k_gemm2(const float* __restrict__ hin,
                                               const float* __restrict__ W,
                                               const float* __restrict__ a_src,
                                               const float* __restrict__ a_dst,
                                               float* __restrict__ xh2,
                                               float* __restrict__ als,
                                               float* __restrict__ ald) {
    __shared__ float hs[32 * F1];
    int tid = threadIdx.x;
    int row0 = blockIdx.x * 32;
    int nrows = N_NODES - row0; if (nrows > 32) nrows = 32;
    float4* hs4 = (float4*)hs;
    const float4* hg = (const float4*)(hin + (size_t)row0 * F1);
    #pragma unroll
    for (int j = 0; j < 8; ++j) {
        int idx = tid + j * 256;
        if ((idx >> 6) < nrows) hs4[idx] = hg[idx];
    }
    __syncthreads();
    int rowg = tid >> 4;
    int col = (tid & 15) * 4;
    float acc[2][4];
    #pragma unroll
    for (int m = 0; m < 2; ++m)
        #pragma unroll
        for (int j = 0; j < 4; ++j) acc[m][j] = 0.f;
    for (int k = 0; k < F1; k += 4) {
        float4 w0 = *(const float4*)(W + (size_t)(k + 0) * OUT_CH + col);
        float4 w1 = *(const float4*)(W + (size_t)(k + 1) * OUT_CH + col);
        float4 w2 = *(const float4*)(W + (size_t)(k + 2) * OUT_CH + col);
        float4 w3 = *(const float4*)(W + (size_t)(k + 3) * OUT_CH + col);
        #pragma unroll
        for (int m = 0; m < 2; ++m) {
            float4 xv = *(const float4*)(hs + (rowg * 2 + m) * F1 + k);
            acc[m][0] = fmaf(xv.x, w0.x, fmaf(xv.y, w1.x, fmaf(xv.z, w2.x, fmaf(xv.w, w3.x, acc[m][0]))));
            acc[m][1] = fmaf(xv.x, w0.y, fmaf(xv.y, w1.y, fmaf(xv.z, w2.y, fmaf(xv.w, w3.y, acc[m][1]))));
            acc[m][2] = fmaf(xv.x, w0.z, fmaf(xv.y, w1.z, fmaf(xv.z, w2.z, fmaf(xv.w, w3.z, acc[m][2]))));
            acc[m][3] = fmaf(xv.x, w0.w, fmaf(xv.y, w1.w, fmaf(xv.z, w2.w, fmaf(xv.w, w3.w, acc[m][3]))));
        }
    }
    int lane = tid & 63;
    float4 asv = *(const float4*)(a_src + col);
    float4 adv = *(const float4*)(a_dst + col);
    #pragma unroll
    for (int m = 0; m < 2; ++m) {
        int row = rowg * 2 + m;
        if (row < nrows) *(float4*)(xh2 + (size_t)(row0 + row) * OUT_CH + col) = *(float4*)acc[m];
        float s = acc[m][0] * asv.x + acc[m][1] * asv.y + acc[m][2] * asv.z + acc[m][3] * asv.w;
        float d = acc[m][0] * adv.x + acc[m][1] * adv.y + acc[m][2] * adv.z + acc[m][3] * adv.w;
        #pragma unroll
        for (int off = 1; off < 16; off <<= 1) {
            s += __shfl_xor(s, off, 64);
            d += __shfl_xor(d, off, 64);
        }
        if ((lane & 15) == 0 && row < nrows) {
            als[row0 + row] = s;
            ald[row0 + row] = d;
        }
    }
}

// ---------------- per-edge alpha, layer 2 ----------------

__global__ void k_alpha2(const int* __restrict__ edge_ids, const int* __restrict__ src,
                         const int* __restrict__ dst, const float* __restrict__ ew,
                         const float* __restrict__ als, const float* __restrict__ ald,
                         const float* __restrict__ de, float* __restrict__ exs) {
    int i = blockIdx.x * 256 + threadIdx.x;
    if (i >= N_EDGES) return;
    int e = edge_ids[i];
    int s = src[e], d = dst[e];
    float a = als[s] + ald[d] + ew[e] * de[HEADS];
    a = a > 0.f ? a : NEG_SLOPE * a;
    exs[i] = __expf(a);
}

// ---------------- fused layer-2 aggregation + bias ----------------

__global__ __launch_bounds__(256) void k_agg2(
        const float* __restrict__ xh2, const float* __restrict__ exs,
        const int* __restrict__ srcs, const int* __restrict__ row_ptr,
        const float* __restrict__ bias, float* __restrict__ out) {
    int node = blockIdx.x * 4 + (threadIdx.x >> 6);
    int lane = threadIdx.x & 63;
    int beg = row_ptr[node], end = row_ptr[node + 1];
    float acc = 0.f, den = 0.f;
    int i = beg;
    for (; i + 8 <= end; i += 8) {
        int s[8];
        #pragma unroll
        for (int j = 0; j < 8; ++j) s[j] = srcs[i + j];
        float e[8];
        #pragma unroll
        for (int j = 0; j < 8; ++j) e[j] = exs[i + j];
        float xv[8];
        #pragma unroll
        for (int j = 0; j < 8; ++j) xv[j] = xh2[(size_t)s[j] * OUT_CH + lane];
        #pragma unroll
        for (int j = 0; j < 8; ++j) {
            den += e[j];
            acc = fmaf(e[j], xv[j], acc);
        }
    }
    for (; i < end; ++i) {
        int s0 = srcs[i];
        float e0 = exs[i];
        den += e0;
        acc = fmaf(e0, xh2[(size_t)s0 * OUT_CH + lane], acc);
    }
    out[(size_t)node * OUT_CH + lane] = acc / (den + 1e-16f) + bias[lane];
}

// ---------------- launch ----------------

extern "C" void kernel_launch(void* const* d_in, const int* in_sizes, int n_in,
                              void* d_out, int out_size, void* d_ws, size_t ws_size,
                              hipStream_t stream) {
    const float* x       = (const float*)d_in[0];
    const float* ew      = (const float*)d_in[1];
    const float* W1      = (const float*)d_in[2];
    const float* a_src1  = (const float*)d_in[3];
    const float* a_dst1  = (const float*)d_in[4];
    const float* a_edge1 = (const float*)d_in[5];
    const float* We1     = (const float*)d_in[6];
    const float* b1      = (const float*)d_in[7];
    const float* W2      = (const float*)d_in[8];
    const float* a_src2  = (const float*)d_in[9];
    const float* a_dst2  = (const float*)d_in[10];
    const float* a_edge2 = (const float*)d_in[11];
    const float* We2     = (const float*)d_in[12];
    const float* b2      = (const float*)d_in[13];
    const int*   eidx    = (const int*)d_in[14];
    const int* esrc = eidx;
    const int* edst = eidx + N_EDGES;
    float* out = (float*)d_out;

    char* p = (char*)d_ws;
    auto alloc = [&](size_t bytes) {
        char* r = p;
        p += (bytes + 255) & ~(size_t)255;
        return r;
    };
    float* accbuf = (float*)alloc((size_t)(N_NODES + 32) * 512 * 4);  // padded rows
    float* h1     = (float*)alloc((size_t)N_NODES * F1 * 4);
    float* xh2    = (float*)alloc((size_t)N_NODES * OUT_CH * 4);
    float* als1   = (float*)alloc((size_t)N_NODES * HEADS * 4);
    float* ald1   = (float*)alloc((size_t)N_NODES * HEADS * 4);
    float* als2   = (float*)alloc((size_t)N_NODES * 4);
    float* ald2   = (float*)alloc((size_t)N_NODES * 4);
    float* WA     = (float*)alloc((size_t)IN_CH * 8 * 4);
    float* de     = (float*)alloc(8 * 4);
    int* counts   = (int*)alloc((size_t)N_NODES * 4);
    int* cursor   = (int*)alloc((size_t)N_NODES * 4);
    int* row_ptr  = (int*)alloc((size_t)(N_NODES + 1) * 4);
    int* edge_ids = (int*)alloc((size_t)N_EDGES * 4);
    float* exs1   = (float*)alloc((size_t)N_EDGES * 4 * 4);
    float* exs2   = (float*)alloc((size_t)N_EDGES * 4);
    int* srcs     = (int*)alloc((size_t)N_EDGES * 4);

    // CSR build
    k_zero2<<<(N_NODES + 255) / 256, 256, 0, stream>>>(counts, cursor);
    k_count<<<N_EDGES / 256, 256, 0, stream>>>(edst, counts);
    k_scan<<<1, 1024, 0, stream>>>(counts, row_ptr);
    k_fill<<<N_EDGES / 256, 256, 0, stream>>>(edst, row_ptr, cursor, edge_ids);
    k_prep<<<1, 1024, 0, stream>>>(W1, a_src1, a_dst1, We1, a_edge1, We2, a_edge2, WA, de);

    // layer 1
    k_dots1<<<(N_NODES + 31) / 32, 256, 0, stream>>>(x, WA, als1, ald1);
    k_alpha1<<<N_EDGES / 256, 256, 0, stream>>>(edge_ids, esrc, edst, ew, als1, ald1, de,
                                                exs1, srcs);
    k_aggx1<<<N_NODES / 4, 256, 0, stream>>>(x, exs1, srcs, row_ptr, accbuf);
    k_hgemm1<<<(N_NODES + 31) / 32, 256, 0, stream>>>(accbuf, W1, b1, h1);

    // layer 2
    k_gemm2<<<(N_NODES + 31) / 32, 256, 0, stream>>>(h1, W2, a_src2, a_dst2, xh2, als2, ald2);
    k_alpha2<<<N_EDGES / 256, 256, 0, stream>>>(edge_ids, esrc, edst, ew, als2, ald2, de, exs2);
    k_agg2<<<N_NODES / 4, 256, 0, stream>>>(xh2, exs2, srcs, row_ptr, b2, out);
}

// Round 5
// 167.198 us; speedup vs baseline: 1.1907x; 1.1907x over previous
//
#include <hip/hip_runtime.h>

constexpr int N_NODES = 10000;
constexpr int N_EDGES = 320000;
constexpr int IN_CH   = 128;
constexpr int HID     = 64;
constexpr int HEADS   = 4;
constexpr int OUT_CH  = 64;
constexpr int F1      = HEADS * HID;   // 256
constexpr float NEG_SLOPE = 0.2f;

// ---------------- CSR build ----------------

__global__ void k_zero2(int* __restrict__ counts, int* __restrict__ cursor) {
    int i = blockIdx.x * 256 + threadIdx.x;
    if (i < N_NODES) { counts[i] = 0; cursor[i] = 0; }
}

__global__ void k_count(const int* __restrict__ dst, int* __restrict__ counts) {
    int e = blockIdx.x * 256 + threadIdx.x;
    if (e < N_EDGES) atomicAdd(&counts[dst[e]], 1);
}

__global__ __launch_bounds__(1024) void k_scan(const int* __restrict__ counts,
                                               int* __restrict__ row_ptr) {
    __shared__ int wsum[16];
    __shared__ int s_carry;
    int tid = threadIdx.x, lane = tid & 63, w = tid >> 6;
    if (tid == 0) s_carry = 0;
    __syncthreads();
    for (int base = 0; base < N_NODES; base += 1024) {
        int i = base + tid;
        int v = (i < N_NODES) ? counts[i] : 0;
        int x = v;
        #pragma unroll
        for (int off = 1; off < 64; off <<= 1) {
            int t = __shfl_up(x, off, 64);
            if (lane >= off) x += t;
        }
        if (lane == 63) wsum[w] = x;
        __syncthreads();
        if (w == 0 && lane < 16) {
            int y = wsum[lane];
            #pragma unroll
            for (int off = 1; off < 16; off <<= 1) {
                int u = __shfl_up(y, off, 64);
                if (lane >= off) y += u;
            }
            wsum[lane] = y;
        }
        __syncthreads();
        int carry = s_carry;
        int woff = w ? wsum[w - 1] : 0;
        if (i < N_NODES) row_ptr[i] = carry + woff + x - v;
        int total = wsum[15];
        __syncthreads();
        if (tid == 0) s_carry = carry + total;
    }
    if (tid == 0) row_ptr[N_NODES] = s_carry;
}

__global__ void k_fill(const int* __restrict__ dst, const int* __restrict__ row_ptr,
                       int* __restrict__ cursor, int* __restrict__ edge_ids) {
    int e = blockIdx.x * 256 + threadIdx.x;
    if (e >= N_EDGES) return;
    int d = dst[e];
    int pos = row_ptr[d] + atomicAdd(&cursor[d], 1);
    edge_ids[pos] = e;
}

// ---------------- de[h] = dot(We_h, a_edge_h) ----------------

__global__ void k_de(const float* __restrict__ We1, const float* __restrict__ ae1,
                     const float* __restrict__ We2, const float* __restrict__ ae2,
                     float* __restrict__ de) {
    int t = threadIdx.x;
    if (t < HEADS) {
        float s = 0.f;
        for (int c = 0; c < HID; ++c) s = fmaf(We1[t * HID + c], ae1[t * HID + c], s);
        de[t] = s;
    } else if (t == HEADS) {
        float s = 0.f;
        for (int c = 0; c < OUT_CH; ++c) s = fmaf(We2[c], ae2[c], s);
        de[HEADS] = s;
    }
}

// ---------------- GEMM1 + fused src/dst dots; stores xh1T[h][node][64] ----------

__global__ __launch_bounds__(256) void k_gemm1(const float* __restrict__ x,
                                               const float* __restrict__ W,
                                               const float* __restrict__ a_src,
                                               const float* __restrict__ a_dst,
                                               float* __restrict__ xh1T,
                                               float* __restrict__ als,
                                               float* __restrict__ ald) {
    __shared__ float xs[32 * IN_CH];                       // 16 KB
    int tid = threadIdx.x;
    int row0 = blockIdx.x * 32;
    int nrows = N_NODES - row0; if (nrows > 32) nrows = 32;
    float4* xs4 = (float4*)xs;
    const float4* xg = (const float4*)(x + (size_t)row0 * IN_CH);
    #pragma unroll
    for (int j = 0; j < 4; ++j) {
        int idx = tid + j * 256;
        if ((idx >> 5) < nrows) xs4[idx] = xg[idx];
    }
    __syncthreads();
    int wv = tid >> 6;
    int lane = tid & 63;
    int col = lane * 4;
    int h = lane >> 4;
    int c = (lane & 15) * 4;
    float acc[8][4];
    #pragma unroll
    for (int m = 0; m < 8; ++m)
        #pragma unroll
        for (int j = 0; j < 4; ++j) acc[m][j] = 0.f;

    for (int k = 0; k < IN_CH; k += 4) {
        float4 w0 = *(const float4*)(W + (size_t)(k + 0) * F1 + col);
        float4 w1 = *(const float4*)(W + (size_t)(k + 1) * F1 + col);
        float4 w2 = *(const float4*)(W + (size_t)(k + 2) * F1 + col);
        float4 w3 = *(const float4*)(W + (size_t)(k + 3) * F1 + col);
        #pragma unroll
        for (int m = 0; m < 8; ++m) {
            float4 xv = *(const float4*)(xs + (wv * 8 + m) * IN_CH + k);
            acc[m][0] = fmaf(xv.x, w0.x, fmaf(xv.y, w1.x, fmaf(xv.z, w2.x, fmaf(xv.w, w3.x, acc[m][0]))));
            acc[m][1] = fmaf(xv.x, w0.y, fmaf(xv.y, w1.y, fmaf(xv.z, w2.y, fmaf(xv.w, w3.y, acc[m][1]))));
            acc[m][2] = fmaf(xv.x, w0.z, fmaf(xv.y, w1.z, fmaf(xv.z, w2.z, fmaf(xv.w, w3.z, acc[m][2]))));
            acc[m][3] = fmaf(xv.x, w0.w, fmaf(xv.y, w1.w, fmaf(xv.z, w2.w, fmaf(xv.w, w3.w, acc[m][3]))));
        }
    }
    float4 asv = *(const float4*)(a_src + h * HID + c);
    float4 adv = *(const float4*)(a_dst + h * HID + c);
    #pragma unroll
    for (int m = 0; m < 8; ++m) {
        int row = wv * 8 + m;
        if (row < nrows)
            *(float4*)(xh1T + ((size_t)h * N_NODES + row0 + row) * HID + c) = *(float4*)acc[m];
        float s = acc[m][0] * asv.x + acc[m][1] * asv.y + acc[m][2] * asv.z + acc[m][3] * asv.w;
        float d = acc[m][0] * adv.x + acc[m][1] * adv.y + acc[m][2] * adv.z + acc[m][3] * adv.w;
        #pragma unroll
        for (int off = 1; off < 16; off <<= 1) {
            s += __shfl_xor(s, off, 64);
            d += __shfl_xor(d, off, 64);
        }
        if ((lane & 15) == 0 && row < nrows) {
            als[(size_t)(row0 + row) * HEADS + h] = s;
            ald[(size_t)(row0 + row) * HEADS + h] = d;
        }
    }
}

// ---------------- per-edge alpha, layer 1; writes exsT[h][csr_i] ----------------

__global__ void k_alpha1(const int* __restrict__ edge_ids, const int* __restrict__ src,
                         const int* __restrict__ dst, const float* __restrict__ ew,
                         const float* __restrict__ als, const float* __restrict__ ald,
                         const float* __restrict__ de,
                         float* __restrict__ exsT, int* __restrict__ srcs) {
    int i = blockIdx.x * 256 + threadIdx.x;
    if (i >= N_EDGES) return;
    int e = edge_ids[i];
    int s = src[e], d = dst[e];
    float w = ew[e];
    float4 as = *(const float4*)(als + (size_t)s * HEADS);
    float4 ad = *(const float4*)(ald + (size_t)d * HEADS);
    float4 dev = *(const float4*)de;
    float4 a;
    a.x = as.x + ad.x + w * dev.x;
    a.y = as.y + ad.y + w * dev.y;
    a.z = as.z + ad.z + w * dev.z;
    a.w = as.w + ad.w + w * dev.w;
    a.x = a.x > 0.f ? a.x : NEG_SLOPE * a.x;
    a.y = a.y > 0.f ? a.y : NEG_SLOPE * a.y;
    a.z = a.z > 0.f ? a.z : NEG_SLOPE * a.z;
    a.w = a.w > 0.f ? a.w : NEG_SLOPE * a.w;
    exsT[0 * N_EDGES + i] = __expf(a.x);
    exsT[1 * N_EDGES + i] = __expf(a.y);
    exsT[2 * N_EDGES + i] = __expf(a.z);
    exsT[3 * N_EDGES + i] = __expf(a.w);
    srcs[i] = s;
}

// ---------------- layer-1 aggregation: wave per (node, head) --------------------
// blockIdx swizzled so head h lands on XCD slots {2h, 2h+1} (blockIdx%8 = XCD).
// Wave: 4 edge-slots x 16 lanes x float4 (64 ch). Cross-slot shfl reduce.

__global__ __launch_bounds__(256) void k_agg1(
        const float* __restrict__ xh1T, const float* __restrict__ exsT,
        const int* __restrict__ srcs, const int* __restrict__ row_ptr,
        const float* __restrict__ bias, float* __restrict__ h1) {
    int b = blockIdx.x;
    int slot8 = b & 7;
    int h = slot8 >> 1;
    int nb = (b >> 3) * 2 + (slot8 & 1);           // 0..2499
    int node = nb * 4 + (threadIdx.x >> 6);
    int lane = threadIdx.x & 63;
    int es = lane >> 4;                            // edge slot
    int c4 = (lane & 15) * 4;                      // channel
    const float* xb = xh1T + (size_t)h * N_NODES * HID;
    const float* eb = exsT + (size_t)h * N_EDGES;
    int beg = row_ptr[node], end = row_ptr[node + 1];
    float4 acc = make_float4(0.f, 0.f, 0.f, 0.f);
    float den = 0.f;
    int i = beg + es;
    for (; i + 4 < end; i += 8) {
        float e0 = eb[i], e1 = eb[i + 4];
        int s0 = srcs[i], s1 = srcs[i + 4];
        float4 x0 = *(const float4*)(xb + (size_t)s0 * HID + c4);
        float4 x1 = *(const float4*)(xb + (size_t)s1 * HID + c4);
        den += e0 + e1;
        acc.x = fmaf(e0, x0.x, fmaf(e1, x1.x, acc.x));
        acc.y = fmaf(e0, x0.y, fmaf(e1, x1.y, acc.y));
        acc.z = fmaf(e0, x0.z, fmaf(e1, x1.z, acc.z));
        acc.w = fmaf(e0, x0.w, fmaf(e1, x1.w, acc.w));
    }
    if (i < end) {
        float e0 = eb[i];
        int s0 = srcs[i];
        float4 x0 = *(const float4*)(xb + (size_t)s0 * HID + c4);
        den += e0;
        acc.x = fmaf(e0, x0.x, acc.x);
        acc.y = fmaf(e0, x0.y, acc.y);
        acc.z = fmaf(e0, x0.z, acc.z);
        acc.w = fmaf(e0, x0.w, acc.w);
    }
    #pragma unroll
    for (int off = 32; off >= 16; off >>= 1) {
        acc.x += __shfl_xor(acc.x, off, 64);
        acc.y += __shfl_xor(acc.y, off, 64);
        acc.z += __shfl_xor(acc.z, off, 64);
        acc.w += __shfl_xor(acc.w, off, 64);
        den   += __shfl_xor(den,   off, 64);
    }
    if (es == 0) {
        float inv = 1.f / (den + 1e-16f);
        int cb = h * HID + c4;
        float4 o;
        o.x = fmaf(acc.x, inv, bias[cb + 0]);
        o.y = fmaf(acc.y, inv, bias[cb + 1]);
        o.z = fmaf(acc.z, inv, bias[cb + 2]);
        o.w = fmaf(acc.w, inv, bias[cb + 3]);
        o.x = o.x > 0.f ? o.x : expm1f(o.x);
        o.y = o.y > 0.f ? o.y : expm1f(o.y);
        o.z = o.z > 0.f ? o.z : expm1f(o.z);
        o.w = o.w > 0.f ? o.w : expm1f(o.w);
        *(float4*)(h1 + (size_t)node * F1 + cb) = o;
    }
}

// ---------------- GEMM2 + fused dots2 ----------------

__global__ __launch_bounds__(256) void k_gemm2(const float* __restrict__ hin,
                                               const float* __restrict__ W,
                                               const float* __restrict__ a_src,
                                               const float* __restrict__ a_dst,
                                               float* __restrict__ xh2,
                                               float* __restrict__ als,
                                               float* __restrict__ ald) {
    __shared__ float hs[32 * F1];
    int tid = threadIdx.x;
    int row0 = blockIdx.x * 32;
    int nrows = N_NODES - row0; if (nrows > 32) nrows = 32;
    float4* hs4 = (float4*)hs;
    const float4* hg = (const float4*)(hin + (size_t)row0 * F1);
    #pragma unroll
    for (int j = 0; j < 8; ++j) {
        int idx = tid + j * 256;
        if ((idx >> 6) < nrows) hs4[idx] = hg[idx];
    }
    __syncthreads();
    int rowg = tid >> 4;
    int col = (tid & 15) * 4;
    float acc[2][4];
    #pragma unroll
    for (int m = 0; m < 2; ++m)
        #pragma unroll
        for (int j = 0; j < 4; ++j) acc[m][j] = 0.f;
    for (int k = 0; k < F1; k += 4) {
        float4 w0 = *(const float4*)(W + (size_t)(k + 0) * OUT_CH + col);
        float4 w1 = *(const float4*)(W + (size_t)(k + 1) * OUT_CH + col);
        float4 w2 = *(const float4*)(W + (size_t)(k + 2) * OUT_CH + col);
        float4 w3 = *(const float4*)(W + (size_t)(k + 3) * OUT_CH + col);
        #pragma unroll
        for (int m = 0; m < 2; ++m) {
            float4 xv = *(const float4*)(hs + (rowg * 2 + m) * F1 + k);
            acc[m][0] = fmaf(xv.x, w0.x, fmaf(xv.y, w1.x, fmaf(xv.z, w2.x, fmaf(xv.w, w3.x, acc[m][0]))));
            acc[m][1] = fmaf(xv.x, w0.y, fmaf(xv.y, w1.y, fmaf(xv.z, w2.y, fmaf(xv.w, w3.y, acc[m][1]))));
            acc[m][2] = fmaf(xv.x, w0.z, fmaf(xv.y, w1.z, fmaf(xv.z, w2.z, fmaf(xv.w, w3.z, acc[m][2]))));
            acc[m][3] = fmaf(xv.x, w0.w, fmaf(xv.y, w1.w, fmaf(xv.z, w2.w, fmaf(xv.w, w3.w, acc[m][3]))));
        }
    }
    int lane = tid & 63;
    float4 asv = *(const float4*)(a_src + col);
    float4 adv = *(const float4*)(a_dst + col);
    #pragma unroll
    for (int m = 0; m < 2; ++m) {
        int row = rowg * 2 + m;
        if (row < nrows) *(float4*)(xh2 + (size_t)(row0 + row) * OUT_CH + col) = *(float4*)acc[m];
        float s = acc[m][0] * asv.x + acc[m][1] * asv.y + acc[m][2] * asv.z + acc[m][3] * asv.w;
        float d = acc[m][0] * adv.x + acc[m][1] * adv.y + acc[m][2] * adv.z + acc[m][3] * adv.w;
        #pragma unroll
        for (int off = 1; off < 16; off <<= 1) {
            s += __shfl_xor(s, off, 64);
            d += __shfl_xor(d, off, 64);
        }
        if ((lane & 15) == 0 && row < nrows) {
            als[row0 + row] = s;
            ald[row0 + row] = d;
        }
    }
}

// ---------------- per-edge alpha, layer 2 ----------------

__global__ void k_alpha2(const int* __restrict__ edge_ids, const int* __restrict__ src,
                         const int* __restrict__ dst, const float* __restrict__ ew,
                         const float* __restrict__ als, const float* __restrict__ ald,
                         const float* __restrict__ de, float* __restrict__ exs) {
    int i = blockIdx.x * 256 + threadIdx.x;
    if (i >= N_EDGES) return;
    int e = edge_ids[i];
    int s = src[e], d = dst[e];
    float a = als[s] + ald[d] + ew[e] * de[HEADS];
    a = a > 0.f ? a : NEG_SLOPE * a;
    exs[i] = __expf(a);
}

// ---------------- layer-2 aggregation: wave per node, 4 slots x 16 lanes ---------

__global__ __launch_bounds__(256) void k_agg2(
        const float* __restrict__ xh2, const float* __restrict__ exs,
        const int* __restrict__ srcs, const int* __restrict__ row_ptr,
        const float* __restrict__ bias, float* __restrict__ out) {
    int node = blockIdx.x * 4 + (threadIdx.x >> 6);
    int lane = threadIdx.x & 63;
    int es = lane >> 4;
    int c4 = (lane & 15) * 4;
    int beg = row_ptr[node], end = row_ptr[node + 1];
    float4 acc = make_float4(0.f, 0.f, 0.f, 0.f);
    float den = 0.f;
    int i = beg + es;
    for (; i + 4 < end; i += 8) {
        float e0 = exs[i], e1 = exs[i + 4];
        int s0 = srcs[i], s1 = srcs[i + 4];
        float4 x0 = *(const float4*)(xh2 + (size_t)s0 * OUT_CH + c4);
        float4 x1 = *(const float4*)(xh2 + (size_t)s1 * OUT_CH + c4);
        den += e0 + e1;
        acc.x = fmaf(e0, x0.x, fmaf(e1, x1.x, acc.x));
        acc.y = fmaf(e0, x0.y, fmaf(e1, x1.y, acc.y));
        acc.z = fmaf(e0, x0.z, fmaf(e1, x1.z, acc.z));
        acc.w = fmaf(e0, x0.w, fmaf(e1, x1.w, acc.w));
    }
    if (i < end) {
        float e0 = exs[i];
        int s0 = srcs[i];
        float4 x0 = *(const float4*)(xh2 + (size_t)s0 * OUT_CH + c4);
        den += e0;
        acc.x = fmaf(e0, x0.x, acc.x);
        acc.y = fmaf(e0, x0.y, acc.y);
        acc.z = fmaf(e0, x0.z, acc.z);
        acc.w = fmaf(e0, x0.w, acc.w);
    }
    #pragma unroll
    for (int off = 32; off >= 16; off >>= 1) {
        acc.x += __shfl_xor(acc.x, off, 64);
        acc.y += __shfl_xor(acc.y, off, 64);
        acc.z += __shfl_xor(acc.z, off, 64);
        acc.w += __shfl_xor(acc.w, off, 64);
        den   += __shfl_xor(den,   off, 64);
    }
    if (es == 0) {
        float inv = 1.f / (den + 1e-16f);
        float4 o;
        o.x = fmaf(acc.x, inv, bias[c4 + 0]);
        o.y = fmaf(acc.y, inv, bias[c4 + 1]);
        o.z = fmaf(acc.z, inv, bias[c4 + 2]);
        o.w = fmaf(acc.w, inv, bias[c4 + 3]);
        *(float4*)(out + (size_t)node * OUT_CH + c4) = o;
    }
}

// ---------------- launch ----------------

extern "C" void kernel_launch(void* const* d_in, const int* in_sizes, int n_in,
                              void* d_out, int out_size, void* d_ws, size_t ws_size,
                              hipStream_t stream) {
    const float* x       = (const float*)d_in[0];
    const float* ew      = (const float*)d_in[1];
    const float* W1      = (const float*)d_in[2];
    const float* a_src1  = (const float*)d_in[3];
    const float* a_dst1  = (const float*)d_in[4];
    const float* a_edge1 = (const float*)d_in[5];
    const float* We1     = (const float*)d_in[6];
    const float* b1      = (const float*)d_in[7];
    const float* W2      = (const float*)d_in[8];
    const float* a_src2  = (const float*)d_in[9];
    const float* a_dst2  = (const float*)d_in[10];
    const float* a_edge2 = (const float*)d_in[11];
    const float* We2     = (const float*)d_in[12];
    const float* b2      = (const float*)d_in[13];
    const int*   eidx    = (const int*)d_in[14];
    const int* esrc = eidx;
    const int* edst = eidx + N_EDGES;
    float* out = (float*)d_out;

    char* p = (char*)d_ws;
    auto alloc = [&](size_t bytes) {
        char* r = p;
        p += (bytes + 255) & ~(size_t)255;
        return r;
    };
    float* xh1T   = (float*)alloc((size_t)N_NODES * F1 * 4);      // head-major
    float* h1     = (float*)alloc((size_t)N_NODES * F1 * 4);
    float* xh2    = (float*)alloc((size_t)N_NODES * OUT_CH * 4);
    float* als1   = (float*)alloc((size_t)N_NODES * HEADS * 4);
    float* ald1   = (float*)alloc((size_t)N_NODES * HEADS * 4);
    float* als2   = (float*)alloc((size_t)N_NODES * 4);
    float* ald2   = (float*)alloc((size_t)N_NODES * 4);
    float* de     = (float*)alloc(8 * 4);
    int* counts   = (int*)alloc((size_t)N_NODES * 4);
    int* cursor   = (int*)alloc((size_t)N_NODES * 4);
    int* row_ptr  = (int*)alloc((size_t)(N_NODES + 1) * 4);
    int* edge_ids = (int*)alloc((size_t)N_EDGES * 4);
    float* exsT1  = (float*)alloc((size_t)N_EDGES * HEADS * 4);   // head-major
    float* exs2   = (float*)alloc((size_t)N_EDGES * 4);
    int* srcs     = (int*)alloc((size_t)N_EDGES * 4);

    // CSR build
    k_zero2<<<(N_NODES + 255) / 256, 256, 0, stream>>>(counts, cursor);
    k_count<<<N_EDGES / 256, 256, 0, stream>>>(edst, counts);
    k_scan<<<1, 1024, 0, stream>>>(counts, row_ptr);
    k_fill<<<N_EDGES / 256, 256, 0, stream>>>(edst, row_ptr, cursor, edge_ids);
    k_de<<<1, 64, 0, stream>>>(We1, a_edge1, We2, a_edge2, de);

    // layer 1
    k_gemm1<<<(N_NODES + 31) / 32, 256, 0, stream>>>(x, W1, a_src1, a_dst1, xh1T, als1, ald1);
    k_alpha1<<<N_EDGES / 256, 256, 0, stream>>>(edge_ids, esrc, edst, ew, als1, ald1, de,
                                                exsT1, srcs);
    k_agg1<<<N_NODES / 4 * HEADS, 256, 0, stream>>>(xh1T, exsT1, srcs, row_ptr, b1, h1);

    // layer 2
    k_gemm2<<<(N_NODES + 31) / 32, 256, 0, stream>>>(h1, W2, a_src2, a_dst2, xh2, als2, ald2);
    k_alpha2<<<N_EDGES / 256, 256, 0, stream>>>(edge_ids, esrc, edst, ew, als2, ald2, de, exs2);
    k_agg2<<<N_NODES / 4, 256, 0, stream>>>(xh2, exs2, srcs, row_ptr, b2, out);
}

// Round 6
// 143.811 us; speedup vs baseline: 1.3843x; 1.1626x over previous
//
#include <hip/hip_runtime.h>

constexpr int N_NODES = 10000;
constexpr int N_EDGES = 320000;
constexpr int IN_CH   = 128;
constexpr int HID     = 64;
constexpr int HEADS   = 4;
constexpr int OUT_CH  = 64;
constexpr int F1      = HEADS * HID;   // 256
constexpr float NEG_SLOPE = 0.2f;
constexpr int GEMM1_BLOCKS = (N_NODES + 31) / 32;   // 313
constexpr int EDGE_BLOCKS  = N_EDGES / 256;         // 1250

// ---------------- fused GEMM1 (+src/dst dots, head-major) ∥ edge count ----------

__global__ __launch_bounds__(256) void k_count_gemm1(
        const float* __restrict__ x, const float* __restrict__ W,
        const float* __restrict__ a_src, const float* __restrict__ a_dst,
        const int* __restrict__ dst,
        float* __restrict__ xh1T, float* __restrict__ alsT, float* __restrict__ aldT,
        int* __restrict__ counts) {
    int bid = blockIdx.x;
    if (bid >= GEMM1_BLOCKS) {
        // ---- edge-count role ----
        int e = (bid - GEMM1_BLOCKS) * 256 + threadIdx.x;
        if (e < N_EDGES) atomicAdd(&counts[dst[e]], 1);
        return;
    }
    // ---- GEMM1 role: [32,128] @ [128,256] ----
    __shared__ float xs[32 * IN_CH];                       // 16 KB
    int tid = threadIdx.x;
    int row0 = bid * 32;
    int nrows = N_NODES - row0; if (nrows > 32) nrows = 32;
    float4* xs4 = (float4*)xs;
    const float4* xg = (const float4*)(x + (size_t)row0 * IN_CH);
    #pragma unroll
    for (int j = 0; j < 4; ++j) {
        int idx = tid + j * 256;
        if ((idx >> 5) < nrows) xs4[idx] = xg[idx];
    }
    __syncthreads();
    int wv = tid >> 6;
    int lane = tid & 63;
    int col = lane * 4;
    int h = lane >> 4;
    int c = (lane & 15) * 4;
    float acc[8][4];
    #pragma unroll
    for (int m = 0; m < 8; ++m)
        #pragma unroll
        for (int j = 0; j < 4; ++j) acc[m][j] = 0.f;

    for (int k = 0; k < IN_CH; k += 4) {
        float4 w0 = *(const float4*)(W + (size_t)(k + 0) * F1 + col);
        float4 w1 = *(const float4*)(W + (size_t)(k + 1) * F1 + col);
        float4 w2 = *(const float4*)(W + (size_t)(k + 2) * F1 + col);
        float4 w3 = *(const float4*)(W + (size_t)(k + 3) * F1 + col);
        #pragma unroll
        for (int m = 0; m < 8; ++m) {
            float4 xv = *(const float4*)(xs + (wv * 8 + m) * IN_CH + k);
            acc[m][0] = fmaf(xv.x, w0.x, fmaf(xv.y, w1.x, fmaf(xv.z, w2.x, fmaf(xv.w, w3.x, acc[m][0]))));
            acc[m][1] = fmaf(xv.x, w0.y, fmaf(xv.y, w1.y, fmaf(xv.z, w2.y, fmaf(xv.w, w3.y, acc[m][1]))));
            acc[m][2] = fmaf(xv.x, w0.z, fmaf(xv.y, w1.z, fmaf(xv.z, w2.z, fmaf(xv.w, w3.z, acc[m][2]))));
            acc[m][3] = fmaf(xv.x, w0.w, fmaf(xv.y, w1.w, fmaf(xv.z, w2.w, fmaf(xv.w, w3.w, acc[m][3]))));
        }
    }
    float4 asv = *(const float4*)(a_src + h * HID + c);
    float4 adv = *(const float4*)(a_dst + h * HID + c);
    #pragma unroll
    for (int m = 0; m < 8; ++m) {
        int row = wv * 8 + m;
        if (row < nrows)
            *(float4*)(xh1T + ((size_t)h * N_NODES + row0 + row) * HID + c) = *(float4*)acc[m];
        float s = acc[m][0] * asv.x + acc[m][1] * asv.y + acc[m][2] * asv.z + acc[m][3] * asv.w;
        float d = acc[m][0] * adv.x + acc[m][1] * adv.y + acc[m][2] * adv.z + acc[m][3] * adv.w;
        #pragma unroll
        for (int off = 1; off < 16; off <<= 1) {
            s += __shfl_xor(s, off, 64);
            d += __shfl_xor(d, off, 64);
        }
        if ((lane & 15) == 0 && row < nrows) {
            alsT[(size_t)h * N_NODES + row0 + row] = s;
            aldT[(size_t)h * N_NODES + row0 + row] = d;
        }
    }
}

// ---------------- scan (prefetched, 2 barriers) + de tail ----------------

__global__ __launch_bounds__(1024) void k_scan_de(
        const int* __restrict__ counts, int* __restrict__ row_ptr,
        const float* __restrict__ We1, const float* __restrict__ ae1,
        const float* __restrict__ We2, const float* __restrict__ ae2,
        float* __restrict__ de) {
    __shared__ int wsum[160];
    int tid = threadIdx.x, lane = tid & 63, w = tid >> 6;
    int v[10], xinc[10];
    #pragma unroll
    for (int ch = 0; ch < 10; ++ch) {
        int i = ch * 1024 + tid;
        v[ch] = (i < N_NODES) ? counts[i] : 0;       // 10 loads in flight
    }
    #pragma unroll
    for (int ch = 0; ch < 10; ++ch) {
        int xv = v[ch];
        #pragma unroll
        for (int off = 1; off < 64; off <<= 1) {
            int t = __shfl_up(xv, off, 64);
            if (lane >= off) xv += t;
        }
        xinc[ch] = xv;
        if (lane == 63) wsum[ch * 16 + w] = xv;      // wave totals
    }
    __syncthreads();
    if (w == 0) {
        int carry = 0;
        for (int base = 0; base < 160; base += 64) {
            int idx = base + lane;
            int y = (idx < 160) ? wsum[idx] : 0;
            int yi = y;
            #pragma unroll
            for (int off = 1; off < 64; off <<= 1) {
                int t = __shfl_up(yi, off, 64);
                if (lane >= off) yi += t;
            }
            if (idx < 160) wsum[idx] = carry + yi - y;   // exclusive
            carry += __shfl(yi, 63, 64);
        }
    }
    __syncthreads();
    #pragma unroll
    for (int ch = 0; ch < 10; ++ch) {
        int i = ch * 1024 + tid;
        if (i < N_NODES) row_ptr[i] = wsum[ch * 16 + w] + xinc[ch] - v[ch];
    }
    if (tid == 0) row_ptr[N_NODES] = N_EDGES;
    if (tid < HEADS) {
        float s = 0.f;
        for (int c2 = 0; c2 < HID; ++c2) s = fmaf(We1[tid * HID + c2], ae1[tid * HID + c2], s);
        de[tid] = s;
    } else if (tid == HEADS) {
        float s = 0.f;
        for (int c2 = 0; c2 < OUT_CH; ++c2) s = fmaf(We2[c2], ae2[c2], s);
        de[HEADS] = s;
    }
}

// ---------------- fill: CSR-ordered srcs + edge weights ----------------

__global__ void k_fill(const int* __restrict__ src, const int* __restrict__ dst,
                       const float* __restrict__ ew,
                       const int* __restrict__ row_ptr, int* __restrict__ cursor,
                       int* __restrict__ srcs, float* __restrict__ ewc) {
    int e = blockIdx.x * 256 + threadIdx.x;
    if (e >= N_EDGES) return;
    int d = dst[e];
    int pos = row_ptr[d] + atomicAdd(&cursor[d], 1);
    srcs[pos] = src[e];
    ewc[pos] = ew[e];
}

// ---------------- layer-1 agg, fused alpha: wave per (node, head), XCD-bound ----

__global__ __launch_bounds__(256) void k_agg1(
        const float* __restrict__ xh1T, const float* __restrict__ alsT,
        const float* __restrict__ aldT, const float* __restrict__ ewc,
        const int* __restrict__ srcs, const int* __restrict__ row_ptr,
        const float* __restrict__ de, const float* __restrict__ bias,
        float* __restrict__ h1) {
    int b = blockIdx.x;
    int slot8 = b & 7;
    int h = slot8 >> 1;
    int nb = (b >> 3) * 2 + (slot8 & 1);           // 0..2499
    int node = nb * 4 + (threadIdx.x >> 6);
    int lane = threadIdx.x & 63;
    int es = lane >> 4;                            // edge slot
    int c4 = (lane & 15) * 4;                      // channel
    const float* xb   = xh1T + (size_t)h * N_NODES * HID;
    const float* alsb = alsT + (size_t)h * N_NODES;
    float deh  = de[h];
    float aldv = aldT[(size_t)h * N_NODES + node];
    int beg = row_ptr[node], end = row_ptr[node + 1];
    float4 acc = make_float4(0.f, 0.f, 0.f, 0.f);
    float den = 0.f;
    int i = beg + es;
    for (; i + 4 < end; i += 8) {
        int s0 = srcs[i], s1 = srcs[i + 4];
        float w0 = ewc[i], w1 = ewc[i + 4];
        float a0 = alsb[s0] + aldv + w0 * deh;
        float a1 = alsb[s1] + aldv + w1 * deh;
        a0 = a0 > 0.f ? a0 : NEG_SLOPE * a0;
        a1 = a1 > 0.f ? a1 : NEG_SLOPE * a1;
        float e0 = __expf(a0), e1 = __expf(a1);
        float4 x0 = *(const float4*)(xb + (size_t)s0 * HID + c4);
        float4 x1 = *(const float4*)(xb + (size_t)s1 * HID + c4);
        den += e0 + e1;
        acc.x = fmaf(e0, x0.x, fmaf(e1, x1.x, acc.x));
        acc.y = fmaf(e0, x0.y, fmaf(e1, x1.y, acc.y));
        acc.z = fmaf(e0, x0.z, fmaf(e1, x1.z, acc.z));
        acc.w = fmaf(e0, x0.w, fmaf(e1, x1.w, acc.w));
    }
    if (i < end) {
        int s0 = srcs[i];
        float w0 = ewc[i];
        float a0 = alsb[s0] + aldv + w0 * deh;
        a0 = a0 > 0.f ? a0 : NEG_SLOPE * a0;
        float e0 = __expf(a0);
        float4 x0 = *(const float4*)(xb + (size_t)s0 * HID + c4);
        den += e0;
        acc.x = fmaf(e0, x0.x, acc.x);
        acc.y = fmaf(e0, x0.y, acc.y);
        acc.z = fmaf(e0, x0.z, acc.z);
        acc.w = fmaf(e0, x0.w, acc.w);
    }
    #pragma unroll
    for (int off = 32; off >= 16; off >>= 1) {
        acc.x += __shfl_xor(acc.x, off, 64);
        acc.y += __shfl_xor(acc.y, off, 64);
        acc.z += __shfl_xor(acc.z, off, 64);
        acc.w += __shfl_xor(acc.w, off, 64);
        den   += __shfl_xor(den,   off, 64);
    }
    if (es == 0) {
        float inv = 1.f / (den + 1e-16f);
        int cb = h * HID + c4;
        float4 o;
        o.x = fmaf(acc.x, inv, bias[cb + 0]);
        o.y = fmaf(acc.y, inv, bias[cb + 1]);
        o.z = fmaf(acc.z, inv, bias[cb + 2]);
        o.w = fmaf(acc.w, inv, bias[cb + 3]);
        o.x = o.x > 0.f ? o.x : expm1f(o.x);
        o.y = o.y > 0.f ? o.y : expm1f(o.y);
        o.z = o.z > 0.f ? o.z : expm1f(o.z);
        o.w = o.w > 0.f ? o.w : expm1f(o.w);
        *(float4*)(h1 + (size_t)node * F1 + cb) = o;
    }
}

// ---------------- GEMM2 + fused dots2 ----------------

__global__ __launch_bounds__(256) void k_gemm2(const float* __restrict__ hin,
                                               const float* __restrict__ W,
                                               const float* __restrict__ a_src,
                                               const float* __restrict__ a_dst,
                                               float* __restrict__ xh2,
                                               float* __restrict__ als,
                                               float* __restrict__ ald) {
    __shared__ float hs[32 * F1];
    int tid = threadIdx.x;
    int row0 = blockIdx.x * 32;
    int nrows = N_NODES - row0; if (nrows > 32) nrows = 32;
    float4* hs4 = (float4*)hs;
    const float4* hg = (const float4*)(hin + (size_t)row0 * F1);
    #pragma unroll
    for (int j = 0; j < 8; ++j) {
        int idx = tid + j * 256;
        if ((idx >> 6) < nrows) hs4[idx] = hg[idx];
    }
    __syncthreads();
    int rowg = tid >> 4;
    int col = (tid & 15) * 4;
    float acc[2][4];
    #pragma unroll
    for (int m = 0; m < 2; ++m)
        #pragma unroll
        for (int j = 0; j < 4; ++j) acc[m][j] = 0.f;
    for (int k = 0; k < F1; k += 4) {
        float4 w0 = *(const float4*)(W + (size_t)(k + 0) * OUT_CH + col);
        float4 w1 = *(const float4*)(W + (size_t)(k + 1) * OUT_CH + col);
        float4 w2 = *(const float4*)(W + (size_t)(k + 2) * OUT_CH + col);
        float4 w3 = *(const float4*)(W + (size_t)(k + 3) * OUT_CH + col);
        #pragma unroll
        for (int m = 0; m < 2; ++m) {
            float4 xv = *(const float4*)(hs + (rowg * 2 + m) * F1 + k);
            acc[m][0] = fmaf(xv.x, w0.x, fmaf(xv.y, w1.x, fmaf(xv.z, w2.x, fmaf(xv.w, w3.x, acc[m][0]))));
            acc[m][1] = fmaf(xv.x, w0.y, fmaf(xv.y, w1.y, fmaf(xv.z, w2.y, fmaf(xv.w, w3.y, acc[m][1]))));
            acc[m][2] = fmaf(xv.x, w0.z, fmaf(xv.y, w1.z, fmaf(xv.z, w2.z, fmaf(xv.w, w3.z, acc[m][2]))));
            acc[m][3] = fmaf(xv.x, w0.w, fmaf(xv.y, w1.w, fmaf(xv.z, w2.w, fmaf(xv.w, w3.w, acc[m][3]))));
        }
    }
    int lane = tid & 63;
    float4 asv = *(const float4*)(a_src + col);
    float4 adv = *(const float4*)(a_dst + col);
    #pragma unroll
    for (int m = 0; m < 2; ++m) {
        int row = rowg * 2 + m;
        if (row < nrows) *(float4*)(xh2 + (size_t)(row0 + row) * OUT_CH + col) = *(float4*)acc[m];
        float s = acc[m][0] * asv.x + acc[m][1] * asv.y + acc[m][2] * asv.z + acc[m][3] * asv.w;
        float d = acc[m][0] * adv.x + acc[m][1] * adv.y + acc[m][2] * adv.z + acc[m][3] * adv.w;
        #pragma unroll
        for (int off = 1; off < 16; off <<= 1) {
            s += __shfl_xor(s, off, 64);
            d += __shfl_xor(d, off, 64);
        }
        if ((lane & 15) == 0 && row < nrows) {
            als[row0 + row] = s;
            ald[row0 + row] = d;
        }
    }
}

// ---------------- layer-2 agg, fused alpha: wave per node ----------------

__global__ __launch_bounds__(256) void k_agg2(
        const float* __restrict__ xh2, const float* __restrict__ als,
        const float* __restrict__ ald, const float* __restrict__ ewc,
        const int* __restrict__ srcs, const int* __restrict__ row_ptr,
        const float* __restrict__ de, const float* __restrict__ bias,
        float* __restrict__ out) {
    int node = blockIdx.x * 4 + (threadIdx.x >> 6);
    int lane = threadIdx.x & 63;
    int es = lane >> 4;
    int c4 = (lane & 15) * 4;
    float de2  = de[HEADS];
    float aldv = ald[node];
    int beg = row_ptr[node], end = row_ptr[node + 1];
    float4 acc = make_float4(0.f, 0.f, 0.f, 0.f);
    float den = 0.f;
    int i = beg + es;
    for (; i + 4 < end; i += 8) {
        int s0 = srcs[i], s1 = srcs[i + 4];
        float w0 = ewc[i], w1 = ewc[i + 4];
        float a0 = als[s0] + aldv + w0 * de2;
        float a1 = als[s1] + aldv + w1 * de2;
        a0 = a0 > 0.f ? a0 : NEG_SLOPE * a0;
        a1 = a1 > 0.f ? a1 : NEG_SLOPE * a1;
        float e0 = __expf(a0), e1 = __expf(a1);
        float4 x0 = *(const float4*)(xh2 + (size_t)s0 * OUT_CH + c4);
        float4 x1 = *(const float4*)(xh2 + (size_t)s1 * OUT_CH + c4);
        den += e0 + e1;
        acc.x = fmaf(e0, x0.x, fmaf(e1, x1.x, acc.x));
        acc.y = fmaf(e0, x0.y, fmaf(e1, x1.y, acc.y));
        acc.z = fmaf(e0, x0.z, fmaf(e1, x1.z, acc.z));
        acc.w = fmaf(e0, x0.w, fmaf(e1, x1.w, acc.w));
    }
    if (i < end) {
        int s0 = srcs[i];
        float w0 = ewc[i];
        float a0 = als[s0] + aldv + w0 * de2;
        a0 = a0 > 0.f ? a0 : NEG_SLOPE * a0;
        float e0 = __expf(a0);
        float4 x0 = *(const float4*)(xh2 + (size_t)s0 * OUT_CH + c4);
        den += e0;
        acc.x = fmaf(e0, x0.x, acc.x);
        acc.y = fmaf(e0, x0.y, acc.y);
        acc.z = fmaf(e0, x0.z, acc.z);
        acc.w = fmaf(e0, x0.w, acc.w);
    }
    #pragma unroll
    for (int off = 32; off >= 16; off >>= 1) {
        acc.x += __shfl_xor(acc.x, off, 64);
        acc.y += __shfl_xor(acc.y, off, 64);
        acc.z += __shfl_xor(acc.z, off, 64);
        acc.w += __shfl_xor(acc.w, off, 64);
        den   += __shfl_xor(den,   off, 64);
    }
    if (es == 0) {
        float inv = 1.f / (den + 1e-16f);
        float4 o;
        o.x = fmaf(acc.x, inv, bias[c4 + 0]);
        o.y = fmaf(acc.y, inv, bias[c4 + 1]);
        o.z = fmaf(acc.z, inv, bias[c4 + 2]);
        o.w = fmaf(acc.w, inv, bias[c4 + 3]);
        *(float4*)(out + (size_t)node * OUT_CH + c4) = o;
    }
}

// ---------------- launch ----------------

extern "C" void kernel_launch(void* const* d_in, const int* in_sizes, int n_in,
                              void* d_out, int out_size, void* d_ws, size_t ws_size,
                              hipStream_t stream) {
    const float* x       = (const float*)d_in[0];
    const float* ew      = (const float*)d_in[1];
    const float* W1      = (const float*)d_in[2];
    const float* a_src1  = (const float*)d_in[3];
    const float* a_dst1  = (const float*)d_in[4];
    const float* a_edge1 = (const float*)d_in[5];
    const float* We1     = (const float*)d_in[6];
    const float* b1      = (const float*)d_in[7];
    const float* W2      = (const float*)d_in[8];
    const float* a_src2  = (const float*)d_in[9];
    const float* a_dst2  = (const float*)d_in[10];
    const float* a_edge2 = (const float*)d_in[11];
    const float* We2     = (const float*)d_in[12];
    const float* b2      = (const float*)d_in[13];
    const int*   eidx    = (const int*)d_in[14];
    const int* esrc = eidx;
    const int* edst = eidx + N_EDGES;
    float* out = (float*)d_out;

    char* p = (char*)d_ws;
    auto alloc = [&](size_t bytes) {
        char* r = p;
        p += (bytes + 255) & ~(size_t)255;
        return r;
    };
    float* xh1T   = (float*)alloc((size_t)N_NODES * F1 * 4);      // head-major
    float* h1     = (float*)alloc((size_t)N_NODES * F1 * 4);
    float* xh2    = (float*)alloc((size_t)N_NODES * OUT_CH * 4);
    float* alsT   = (float*)alloc((size_t)N_NODES * HEADS * 4);   // [h][node]
    float* aldT   = (float*)alloc((size_t)N_NODES * HEADS * 4);
    float* als2   = (float*)alloc((size_t)N_NODES * 4);
    float* ald2   = (float*)alloc((size_t)N_NODES * 4);
    float* de     = (float*)alloc(8 * 4);
    int* counts   = (int*)alloc((size_t)N_NODES * 4);             // adjacent with cursor!
    int* cursor   = (int*)alloc((size_t)N_NODES * 4);
    int* row_ptr  = (int*)alloc((size_t)(N_NODES + 1) * 4);
    int* srcs     = (int*)alloc((size_t)N_EDGES * 4);
    float* ewc    = (float*)alloc((size_t)N_EDGES * 4);

    // zero counts+cursor (adjacent, each padded to 40192 B)
    hipMemsetAsync(counts, 0, 2 * 40192, stream);

    // count ∥ GEMM1 (+dots1)
    k_count_gemm1<<<GEMM1_BLOCKS + EDGE_BLOCKS, 256, 0, stream>>>(
        x, W1, a_src1, a_dst1, edst, xh1T, alsT, aldT, counts);

    // scan + de
    k_scan_de<<<1, 1024, 0, stream>>>(counts, row_ptr, We1, a_edge1, We2, a_edge2, de);

    // fill CSR payload (srcs + ewc)
    k_fill<<<EDGE_BLOCKS, 256, 0, stream>>>(esrc, edst, ew, row_ptr, cursor, srcs, ewc);

    // layer-1 agg (fused alpha + softmax + bias + ELU)
    k_agg1<<<N_NODES / 4 * HEADS, 256, 0, stream>>>(
        xh1T, alsT, aldT, ewc, srcs, row_ptr, de, b1, h1);

    // layer 2
    k_gemm2<<<GEMM1_BLOCKS, 256, 0, stream>>>(h1, W2, a_src2, a_dst2, xh2, als2, ald2);
    k_agg2<<<N_NODES / 4, 256, 0, stream>>>(xh2, als2, ald2, ewc, srcs, row_ptr, de, b2, out);
}